// Round 1
// baseline (541.444 us; speedup 1.0000x reference)
//
#include <hip/hip_runtime.h>
#include <hip/hip_bf16.h>

// SoftmaxAttention: B=64, Lc=Lr=512, D=768, fp32 in/out.
//   S = C R^T (3xbf16 split MFMA, fp32 accum)  -> ws
//   attend_c = rowsoftmax(S, rmask) @ R * cmask
//   attend_r = rowsoftmax(S^T, cmask) @ C * rmask
// Exact mask semantics: w_j = m_j exp(t_j - M) / (S_act + EPS*Z),
//   t = s*m, M = max_j t_j, Z = S_act + n_inact*exp(-M), EPS=1e-13.

#define BATCH 64
#define LSEQ 512
#define DMODEL 768

typedef __attribute__((ext_vector_type(4))) float f32x4;
typedef __attribute__((ext_vector_type(8))) short bf16x8;
typedef __attribute__((ext_vector_type(4))) unsigned short u16x4;
typedef __attribute__((ext_vector_type(8))) unsigned short u16x8;

__device__ __forceinline__ unsigned short f2bf(float x) {
  union { float f; unsigned u; } v; v.f = x;
  unsigned r = v.u + 0x7FFFu + ((v.u >> 16) & 1u);
  return (unsigned short)(r >> 16);
}
__device__ __forceinline__ float bf2f(unsigned short h) {
  union { float f; unsigned u; } v; v.u = ((unsigned)h) << 16;
  return v.f;
}

// ---- X [b0+bz][512 n][768 d] fp32  ->  XT [bz][768 d][512 n] bf16 ----
__global__ __launch_bounds__(256) void k_prep_transpose(
    const float* __restrict__ X, unsigned short* __restrict__ XT, int b0) {
  __shared__ float tile[64][65];
  const int bz = blockIdx.z;
  const int n0 = blockIdx.x * 64;
  const int d0 = blockIdx.y * 64;
  const int tid = threadIdx.x;
  const int i = tid >> 2, s4 = (tid & 3) * 4;
  const float* Xb = X + ((size_t)(b0 + bz) * LSEQ + n0 + i) * DMODEL + d0;
#pragma unroll
  for (int kk = 0; kk < 4; ++kk) {
    const int j = kk * 16 + s4;
    const f32x4 v = *(const f32x4*)(Xb + j);
#pragma unroll
    for (int k = 0; k < 4; ++k) tile[i][j + k] = v[k];
  }
  __syncthreads();
  unsigned short* Ob = XT + ((size_t)bz * DMODEL + d0 + i) * LSEQ + n0;
#pragma unroll
  for (int kk = 0; kk < 4; ++kk) {
    const int n = kk * 16 + s4;
    u16x4 h;
#pragma unroll
    for (int k = 0; k < 4; ++k) h[k] = f2bf(tile[n + k][i]);
    *(u16x4*)(Ob + n) = h;
  }
}

// ---- S [bz][512 c][512 r] fp32 -> ST [bz][512 r][512 c] fp32 ----
__global__ __launch_bounds__(256) void k_transpose_s(
    const float* __restrict__ S, float* __restrict__ ST) {
  __shared__ float tile[64][65];
  const int bz = blockIdx.z;
  const int c0 = blockIdx.x * 64;
  const int r0 = blockIdx.y * 64;
  const int tid = threadIdx.x;
  const int i = tid >> 2, s4 = (tid & 3) * 4;
  const float* Sb = S + ((size_t)bz * LSEQ + c0 + i) * LSEQ + r0;
#pragma unroll
  for (int kk = 0; kk < 4; ++kk) {
    const int j = kk * 16 + s4;
    const f32x4 v = *(const f32x4*)(Sb + j);
#pragma unroll
    for (int k = 0; k < 4; ++k) tile[i][j + k] = v[k];
  }
  __syncthreads();
  float* Ob = ST + ((size_t)bz * LSEQ + r0 + i) * LSEQ + c0;
#pragma unroll
  for (int kk = 0; kk < 4; ++kk) {
    const int n = kk * 16 + s4;
    f32x4 v;
#pragma unroll
    for (int k = 0; k < 4; ++k) v[k] = tile[n + k][i];
    *(f32x4*)(Ob + n) = v;
  }
}

// ---- S[bz][c][r] = sum_d C[c][d]*R[r][d], 3xbf16 split, 64x64 tile ----
__global__ __launch_bounds__(256) void k_gemm_s(
    const float* __restrict__ Cg, const float* __restrict__ Rg,
    float* __restrict__ S, int b0) {
  __shared__ unsigned short Ahi[64 * 40];
  __shared__ unsigned short Alo[64 * 40];
  __shared__ unsigned short Bhi[64 * 40];
  __shared__ unsigned short Blo[64 * 40];
  const int bz = blockIdx.z;
  const int b = b0 + bz;
  const int c0 = blockIdx.x * 64;
  const int r0 = blockIdx.y * 64;
  const int tid = threadIdx.x;
  const int lane = tid & 63;
  const int w = tid >> 6;
  const int qm = (w & 1) * 32, qn = (w >> 1) * 32;
  const int l15 = lane & 15, kg = lane >> 4;
  const int srow = tid >> 2, sc = (tid & 3) * 8;
  const float* Cb = Cg + ((size_t)b * LSEQ + c0 + srow) * DMODEL + sc;
  const float* Rb = Rg + ((size_t)b * LSEQ + r0 + srow) * DMODEL + sc;
  f32x4 acc[2][2] = {};
  for (int k0 = 0; k0 < DMODEL; k0 += 32) {
    const f32x4 cva = *(const f32x4*)(Cb + k0);
    const f32x4 cvb = *(const f32x4*)(Cb + k0 + 4);
    const f32x4 rva = *(const f32x4*)(Rb + k0);
    const f32x4 rvb = *(const f32x4*)(Rb + k0 + 4);
    __syncthreads();  // previous iter's MFMA reads done
    {
      u16x4 h0, h1, l0, l1;
#pragma unroll
      for (int k = 0; k < 4; ++k) {
        unsigned short h = f2bf(cva[k]); h0[k] = h; l0[k] = f2bf(cva[k] - bf2f(h));
        h = f2bf(cvb[k]); h1[k] = h; l1[k] = f2bf(cvb[k] - bf2f(h));
      }
      *(u16x4*)&Ahi[srow * 40 + sc] = h0;  *(u16x4*)&Ahi[srow * 40 + sc + 4] = h1;
      *(u16x4*)&Alo[srow * 40 + sc] = l0;  *(u16x4*)&Alo[srow * 40 + sc + 4] = l1;
#pragma unroll
      for (int k = 0; k < 4; ++k) {
        unsigned short h = f2bf(rva[k]); h0[k] = h; l0[k] = f2bf(rva[k] - bf2f(h));
        h = f2bf(rvb[k]); h1[k] = h; l1[k] = f2bf(rvb[k] - bf2f(h));
      }
      *(u16x4*)&Bhi[srow * 40 + sc] = h0;  *(u16x4*)&Bhi[srow * 40 + sc + 4] = h1;
      *(u16x4*)&Blo[srow * 40 + sc] = l0;  *(u16x4*)&Blo[srow * 40 + sc + 4] = l1;
    }
    __syncthreads();
    bf16x8 ah[2], al2[2], bh[2], bl2[2];
#pragma unroll
    for (int f = 0; f < 2; ++f) {
      ah[f]  = *(const bf16x8*)&Ahi[(qm + f * 16 + l15) * 40 + kg * 8];
      al2[f] = *(const bf16x8*)&Alo[(qm + f * 16 + l15) * 40 + kg * 8];
      bh[f]  = *(const bf16x8*)&Bhi[(qn + f * 16 + l15) * 40 + kg * 8];
      bl2[f] = *(const bf16x8*)&Blo[(qn + f * 16 + l15) * 40 + kg * 8];
    }
#pragma unroll
    for (int fm = 0; fm < 2; ++fm)
#pragma unroll
      for (int fn = 0; fn < 2; ++fn) {
        acc[fm][fn] = __builtin_amdgcn_mfma_f32_16x16x32_bf16(ah[fm], bh[fn], acc[fm][fn], 0, 0, 0);
        acc[fm][fn] = __builtin_amdgcn_mfma_f32_16x16x32_bf16(ah[fm], bl2[fn], acc[fm][fn], 0, 0, 0);
        acc[fm][fn] = __builtin_amdgcn_mfma_f32_16x16x32_bf16(al2[fm], bh[fn], acc[fm][fn], 0, 0, 0);
      }
  }
  float* Sb = S + ((size_t)bz * LSEQ + c0) * LSEQ + r0;
  const int r4 = (lane >> 4) * 4;
#pragma unroll
  for (int fm = 0; fm < 2; ++fm)
#pragma unroll
    for (int fn = 0; fn < 2; ++fn)
#pragma unroll
      for (int reg = 0; reg < 4; ++reg)
        Sb[(size_t)(qm + fm * 16 + r4 + reg) * LSEQ + qn + fn * 16 + l15] = acc[fm][fn][reg];
}

// ---- generic masked-softmax + PV.  L[bz][512 m][512 n] fp32 (chunk-local),
//      Vt[bz][768 d][512 n] bf16, out[b][512 m][768 d] = softmax_n(L)*Vt * maskM
__global__ __launch_bounds__(256) void k_attn(
    const float* __restrict__ Lg, const unsigned short* __restrict__ Vt,
    const int* __restrict__ maskN, const int* __restrict__ maskM,
    float* __restrict__ out, int b0) {
  __shared__ unsigned short Wlds[64 * 72];
  __shared__ unsigned short Vlds[256 * 72];
  __shared__ float maskNf[512];
  __shared__ float Mrow[64], Invd[64], maskMf[64];
  __shared__ float s_ninact;
  const int bz = blockIdx.z;
  const int b = b0 + bz;
  const int m0 = blockIdx.x * 64;
  const int nh = blockIdx.y;  // d-third: 0..2
  const int tid = threadIdx.x;
  const int lane = tid & 63;
  const int w = tid >> 6;
  const int l15 = lane & 15, kg = lane >> 4;
  const int row = tid >> 2, seg = tid & 3;

  if (tid == 0) s_ninact = 0.f;
  if (tid < 64) maskMf[tid] = (float)maskM[(size_t)b * LSEQ + m0 + tid];
  __syncthreads();
  float cnt = 0.f;
  for (int j = tid; j < LSEQ; j += 256) {
    const float m = (float)maskN[(size_t)b * LSEQ + j];
    maskNf[j] = m;
    cnt += 1.f - m;
  }
  atomicAdd(&s_ninact, cnt);
  __syncthreads();
  const float ninact = s_ninact;

  // phase 1: per-row max / denom (4 lanes per row)
  const float* Lr = Lg + ((size_t)bz * LSEQ + m0 + row) * LSEQ;
  float mx = -1e30f;
  for (int it = 0; it < 8; ++it) {
    const int j = it * 64 + seg * 16;
#pragma unroll
    for (int q = 0; q < 4; ++q) {
      const f32x4 s4 = *(const f32x4*)(Lr + j + q * 4);
#pragma unroll
      for (int k = 0; k < 4; ++k)
        if (maskNf[j + q * 4 + k] > 0.5f) mx = fmaxf(mx, s4[k]);
    }
  }
  mx = fmaxf(mx, __shfl_xor(mx, 1));
  mx = fmaxf(mx, __shfl_xor(mx, 2));
  const float M = (ninact > 0.5f) ? fmaxf(mx, 0.f) : mx;
  float sum = 0.f;
  for (int it = 0; it < 8; ++it) {
    const int j = it * 64 + seg * 16;
#pragma unroll
    for (int q = 0; q < 4; ++q) {
      const f32x4 s4 = *(const f32x4*)(Lr + j + q * 4);
#pragma unroll
      for (int k = 0; k < 4; ++k)
        sum += maskNf[j + q * 4 + k] * __expf(fminf(s4[k] - M, 0.f));
    }
  }
  sum += __shfl_xor(sum, 1);
  sum += __shfl_xor(sum, 2);
  if (seg == 0) {
    const float Z = sum + ((ninact > 0.5f) ? ninact * __expf(-M) : 0.f);
    Mrow[row] = M;
    Invd[row] = 1.f / (sum + 1e-13f * Z);
  }

  // phase 2: attend[64 x 256] = W @ V^T  (K-tiles of 64 over n)
  f32x4 acc[4][4] = {};
  for (int rt = 0; rt < 8; ++rt) {
    __syncthreads();  // stats ready (rt=0) / prev MFMA reads done (rt>0)
    const float Mr = Mrow[row];
    const float Iv = Invd[row];
#pragma unroll
    for (int v = 0; v < 4; ++v) {
      const int j = rt * 64 + v * 16 + seg * 4;
      const f32x4 s4 = *(const f32x4*)(Lr + j);
      u16x4 hw;
#pragma unroll
      for (int k = 0; k < 4; ++k) {
        const float wv = maskNf[j + k] * __expf(fminf(s4[k] - Mr, 0.f)) * Iv;
        hw[k] = f2bf(wv);
      }
      *(u16x4*)&Wlds[row * 72 + v * 16 + seg * 4] = hw;
    }
    const unsigned short* Vb = Vt + ((size_t)bz * DMODEL + nh * 256) * LSEQ + rt * 64;
#pragma unroll
    for (int p = 0; p < 8; ++p) {
      const int chunk = p * 256 + tid;
      const int dd = chunk >> 3, part = chunk & 7;
      *(u16x8*)&Vlds[dd * 72 + part * 8] = *(const u16x8*)(Vb + (size_t)dd * LSEQ + part * 8);
    }
    __syncthreads();
#pragma unroll
    for (int kk = 0; kk < 2; ++kk) {
      bf16x8 a[4], bb[4];
#pragma unroll
      for (int f = 0; f < 4; ++f)
        a[f] = *(const bf16x8*)&Wlds[(f * 16 + l15) * 72 + kk * 32 + kg * 8];
#pragma unroll
      for (int f = 0; f < 4; ++f)
        bb[f] = *(const bf16x8*)&Vlds[(w * 64 + f * 16 + l15) * 72 + kk * 32 + kg * 8];
#pragma unroll
      for (int fm = 0; fm < 4; ++fm)
#pragma unroll
        for (int fn = 0; fn < 4; ++fn)
          acc[fm][fn] = __builtin_amdgcn_mfma_f32_16x16x32_bf16(a[fm], bb[fn], acc[fm][fn], 0, 0, 0);
    }
  }
  const int r4 = (lane >> 4) * 4;
#pragma unroll
  for (int fm = 0; fm < 4; ++fm)
#pragma unroll
    for (int fn = 0; fn < 4; ++fn)
#pragma unroll
      for (int reg = 0; reg < 4; ++reg) {
        const int rr = fm * 16 + r4 + reg;
        const int col = nh * 256 + w * 64 + fn * 16 + l15;
        out[((size_t)b * LSEQ + m0 + rr) * DMODEL + col] = acc[fm][fn][reg] * maskMf[rr];
      }
}

extern "C" void kernel_launch(void* const* d_in, const int* in_sizes, int n_in,
                              void* d_out, int out_size, void* d_ws, size_t ws_size,
                              hipStream_t stream) {
  const float* context = (const float*)d_in[0];
  const float* response = (const float*)d_in[1];
  const int* cmask = (const int*)d_in[2];
  const int* rmask = (const int*)d_in[3];
  float* out = (float*)d_out;

  // ws per batch: S + ST (fp32 512x512) + RT + CT (bf16 768x512)
  const size_t perBatch = (size_t)2 * LSEQ * LSEQ * 4 + (size_t)2 * DMODEL * LSEQ * 2;
  int nbc = (int)(ws_size / perBatch);
  if (nbc > BATCH) nbc = BATCH;
  if (nbc < 1) nbc = 1;

  char* base = (char*)d_ws;
  float* S = (float*)base;
  float* ST = (float*)(base + (size_t)nbc * LSEQ * LSEQ * 4);
  unsigned short* RT = (unsigned short*)(base + (size_t)2 * nbc * LSEQ * LSEQ * 4);
  unsigned short* CT = RT + (size_t)nbc * DMODEL * LSEQ;

  float* out_c = out;
  float* out_r = out + (size_t)BATCH * LSEQ * DMODEL;

  for (int b0 = 0; b0 < BATCH; b0 += nbc) {
    int nb = BATCH - b0;
    if (nb > nbc) nb = nbc;
    dim3 blk(256);
    k_prep_transpose<<<dim3(8, 12, nb), blk, 0, stream>>>(response, RT, b0);
    k_prep_transpose<<<dim3(8, 12, nb), blk, 0, stream>>>(context, CT, b0);
    k_gemm_s<<<dim3(8, 8, nb), blk, 0, stream>>>(context, response, S, b0);
    k_transpose_s<<<dim3(8, 8, nb), blk, 0, stream>>>(S, ST);
    k_attn<<<dim3(8, 3, nb), blk, 0, stream>>>(S, RT, rmask, cmask, out_c, b0);
    k_attn<<<dim3(8, 3, nb), blk, 0, stream>>>(ST, CT, cmask, rmask, out_r, b0);
  }
}

// Round 2
// 421.335 us; speedup vs baseline: 1.2851x; 1.2851x over previous
//
#include <hip/hip_runtime.h>
#include <hip/hip_bf16.h>

// SoftmaxAttention: B=64, Lc=Lr=512, D=768, fp32 in/out.
//   S = C R^T (3xbf16 split MFMA, fp32 accum)  -> ws
//   W_c = rowsoftmax(S, rmask) bf16 -> ws ; attend_c = W_c @ R * cmask
//   W_r = rowsoftmax(S^T, cmask) bf16 -> ws; attend_r = W_r @ C * rmask
// Mask semantics: w_j = m_j exp(t_j - M) / (S_act + EPS*Z),
//   t = s*m, M = max_j t_j (=max(max_act,0) if any inactive),
//   Z = S_act + n_inact*exp(-M), EPS=1e-13.

#define BATCH 64
#define LSEQ 512
#define DMODEL 768

typedef __attribute__((ext_vector_type(4))) float f32x4;
typedef __attribute__((ext_vector_type(8))) short bf16x8;
typedef __attribute__((ext_vector_type(4))) unsigned short u16x4;
typedef __attribute__((ext_vector_type(8))) unsigned short u16x8;

__device__ __forceinline__ unsigned short f2bf(float x) {
  union { float f; unsigned u; } v; v.f = x;
  unsigned r = v.u + 0x7FFFu + ((v.u >> 16) & 1u);
  return (unsigned short)(r >> 16);
}
__device__ __forceinline__ float bf2f(unsigned short h) {
  union { float f; unsigned u; } v; v.u = ((unsigned)h) << 16;
  return v.f;
}
__device__ __forceinline__ void gload16(const void* g, void* l) {
  __builtin_amdgcn_global_load_lds(
      (const __attribute__((address_space(1))) unsigned int*)g,
      (__attribute__((address_space(3))) unsigned int*)l, 16, 0, 0);
}

// ---- X [b0+bz][512 n][768 d] fp32  ->  XT [bz][768 d][512 n] bf16 ----
__global__ __launch_bounds__(256) void k_prep_transpose(
    const float* __restrict__ X, unsigned short* __restrict__ XT, int b0) {
  __shared__ float tile[64][65];
  const int bz = blockIdx.z;
  const int n0 = blockIdx.x * 64;
  const int d0 = blockIdx.y * 64;
  const int tid = threadIdx.x;
  const int i = tid >> 2, s4 = (tid & 3) * 4;
  const float* Xb = X + ((size_t)(b0 + bz) * LSEQ + n0 + i) * DMODEL + d0;
#pragma unroll
  for (int kk = 0; kk < 4; ++kk) {
    const int j = kk * 16 + s4;
    const f32x4 v = *(const f32x4*)(Xb + j);
#pragma unroll
    for (int k = 0; k < 4; ++k) tile[i][j + k] = v[k];
  }
  __syncthreads();
  unsigned short* Ob = XT + ((size_t)bz * DMODEL + d0 + i) * LSEQ + n0;
#pragma unroll
  for (int kk = 0; kk < 4; ++kk) {
    const int n = kk * 16 + s4;
    u16x4 h;
#pragma unroll
    for (int k = 0; k < 4; ++k) h[k] = f2bf(tile[n + k][i]);
    *(u16x4*)(Ob + n) = h;
  }
}

// ---- S [bz][512 c][512 r] fp32 -> ST [bz][512 r][512 c] fp32 ----
__global__ __launch_bounds__(256) void k_transpose_s(
    const float* __restrict__ S, float* __restrict__ ST) {
  __shared__ float tile[64][65];
  const int bz = blockIdx.z;
  const int c0 = blockIdx.x * 64;
  const int r0 = blockIdx.y * 64;
  const int tid = threadIdx.x;
  const int i = tid >> 2, s4 = (tid & 3) * 4;
  const float* Sb = S + ((size_t)bz * LSEQ + c0 + i) * LSEQ + r0;
#pragma unroll
  for (int kk = 0; kk < 4; ++kk) {
    const int j = kk * 16 + s4;
    const f32x4 v = *(const f32x4*)(Sb + j);
#pragma unroll
    for (int k = 0; k < 4; ++k) tile[i][j + k] = v[k];
  }
  __syncthreads();
  float* Ob = ST + ((size_t)bz * LSEQ + r0 + i) * LSEQ + c0;
#pragma unroll
  for (int kk = 0; kk < 4; ++kk) {
    const int n = kk * 16 + s4;
    f32x4 v;
#pragma unroll
    for (int k = 0; k < 4; ++k) v[k] = tile[n + k][i];
    *(f32x4*)(Ob + n) = v;
  }
}

// ---- S[bz][c][r] = sum_d C[c][d]*R[r][d], 3xbf16 split, 64x64 tile ----
__global__ __launch_bounds__(256) void k_gemm_s(
    const float* __restrict__ Cg, const float* __restrict__ Rg,
    float* __restrict__ S, int b0) {
  __shared__ unsigned short Ahi[64 * 40];
  __shared__ unsigned short Alo[64 * 40];
  __shared__ unsigned short Bhi[64 * 40];
  __shared__ unsigned short Blo[64 * 40];
  const int bz = blockIdx.z;
  const int b = b0 + bz;
  const int c0 = blockIdx.x * 64;
  const int r0 = blockIdx.y * 64;
  const int tid = threadIdx.x;
  const int lane = tid & 63;
  const int w = tid >> 6;
  const int qm = (w & 1) * 32, qn = (w >> 1) * 32;
  const int l15 = lane & 15, kg = lane >> 4;
  const int srow = tid >> 2, sc = (tid & 3) * 8;
  const float* Cb = Cg + ((size_t)b * LSEQ + c0 + srow) * DMODEL + sc;
  const float* Rb = Rg + ((size_t)b * LSEQ + r0 + srow) * DMODEL + sc;
  f32x4 acc[2][2] = {};
  for (int k0 = 0; k0 < DMODEL; k0 += 32) {
    const f32x4 cva = *(const f32x4*)(Cb + k0);
    const f32x4 cvb = *(const f32x4*)(Cb + k0 + 4);
    const f32x4 rva = *(const f32x4*)(Rb + k0);
    const f32x4 rvb = *(const f32x4*)(Rb + k0 + 4);
    __syncthreads();  // previous iter's MFMA reads done
    {
      u16x4 h0, h1, l0, l1;
#pragma unroll
      for (int k = 0; k < 4; ++k) {
        unsigned short h = f2bf(cva[k]); h0[k] = h; l0[k] = f2bf(cva[k] - bf2f(h));
        h = f2bf(cvb[k]); h1[k] = h; l1[k] = f2bf(cvb[k] - bf2f(h));
      }
      *(u16x4*)&Ahi[srow * 40 + sc] = h0;  *(u16x4*)&Ahi[srow * 40 + sc + 4] = h1;
      *(u16x4*)&Alo[srow * 40 + sc] = l0;  *(u16x4*)&Alo[srow * 40 + sc + 4] = l1;
#pragma unroll
      for (int k = 0; k < 4; ++k) {
        unsigned short h = f2bf(rva[k]); h0[k] = h; l0[k] = f2bf(rva[k] - bf2f(h));
        h = f2bf(rvb[k]); h1[k] = h; l1[k] = f2bf(rvb[k] - bf2f(h));
      }
      *(u16x4*)&Bhi[srow * 40 + sc] = h0;  *(u16x4*)&Bhi[srow * 40 + sc + 4] = h1;
      *(u16x4*)&Blo[srow * 40 + sc] = l0;  *(u16x4*)&Blo[srow * 40 + sc + 4] = l1;
    }
    __syncthreads();
    bf16x8 ah[2], al2[2], bh[2], bl2[2];
#pragma unroll
    for (int f = 0; f < 2; ++f) {
      ah[f]  = *(const bf16x8*)&Ahi[(qm + f * 16 + l15) * 40 + kg * 8];
      al2[f] = *(const bf16x8*)&Alo[(qm + f * 16 + l15) * 40 + kg * 8];
      bh[f]  = *(const bf16x8*)&Bhi[(qn + f * 16 + l15) * 40 + kg * 8];
      bl2[f] = *(const bf16x8*)&Blo[(qn + f * 16 + l15) * 40 + kg * 8];
    }
#pragma unroll
    for (int fm = 0; fm < 2; ++fm)
#pragma unroll
      for (int fn = 0; fn < 2; ++fn) {
        acc[fm][fn] = __builtin_amdgcn_mfma_f32_16x16x32_bf16(ah[fm], bh[fn], acc[fm][fn], 0, 0, 0);
        acc[fm][fn] = __builtin_amdgcn_mfma_f32_16x16x32_bf16(ah[fm], bl2[fn], acc[fm][fn], 0, 0, 0);
        acc[fm][fn] = __builtin_amdgcn_mfma_f32_16x16x32_bf16(al2[fm], bh[fn], acc[fm][fn], 0, 0, 0);
      }
  }
  float* Sb = S + ((size_t)bz * LSEQ + c0) * LSEQ + r0;
  const int r4 = (lane >> 4) * 4;
#pragma unroll
  for (int fm = 0; fm < 2; ++fm)
#pragma unroll
    for (int fn = 0; fn < 2; ++fn)
#pragma unroll
      for (int reg = 0; reg < 4; ++reg)
        Sb[(size_t)(qm + fm * 16 + r4 + reg) * LSEQ + qn + fn * 16 + l15] = acc[fm][fn][reg];
}

// ---- masked row-softmax: L[bz][512][512] fp32 -> W[bz][512][512] bf16 ----
// one block = 64 rows (16 per wave); one pass, row held in registers
__global__ __launch_bounds__(256) void k_softmax(
    const float* __restrict__ Lg, const int* __restrict__ maskN,
    unsigned short* __restrict__ Wg, int b0) {
  __shared__ float maskNf[LSEQ];
  __shared__ float s_ninact;
  const int bz = blockIdx.z;
  const int b = b0 + bz;
  const int r0 = blockIdx.x * 64;
  const int tid = threadIdx.x;
  const int lane = tid & 63;
  const int w = tid >> 6;
  if (tid == 0) s_ninact = 0.f;
  __syncthreads();
  float cnt = 0.f;
  for (int j = tid; j < LSEQ; j += 256) {
    const float m = (float)maskN[(size_t)b * LSEQ + j];
    maskNf[j] = m;
    cnt += 1.f - m;
  }
#pragma unroll
  for (int s = 1; s < 64; s <<= 1) cnt += __shfl_xor(cnt, s);
  if (lane == 0) atomicAdd(&s_ninact, cnt);
  __syncthreads();
  const float ninact = s_ninact;
  float mk[8];
#pragma unroll
  for (int k = 0; k < 8; ++k) mk[k] = maskNf[lane * 8 + k];

  for (int rr = 0; rr < 16; ++rr) {
    const int r = r0 + w * 16 + rr;
    const float* Lr = Lg + ((size_t)bz * LSEQ + r) * LSEQ + lane * 8;
    const f32x4 v0 = *(const f32x4*)(Lr);
    const f32x4 v1 = *(const f32x4*)(Lr + 4);
    float v[8];
#pragma unroll
    for (int k = 0; k < 4; ++k) { v[k] = v0[k]; v[k + 4] = v1[k]; }
    float mx = -1e30f;
#pragma unroll
    for (int k = 0; k < 8; ++k)
      if (mk[k] > 0.5f) mx = fmaxf(mx, v[k]);
#pragma unroll
    for (int s = 1; s < 64; s <<= 1) mx = fmaxf(mx, __shfl_xor(mx, s));
    const float M = (ninact > 0.5f) ? fmaxf(mx, 0.f) : mx;
    float p[8];
    float sum = 0.f;
#pragma unroll
    for (int k = 0; k < 8; ++k) {
      p[k] = mk[k] * __expf(fminf(v[k] - M, 0.f));
      sum += p[k];
    }
#pragma unroll
    for (int s = 1; s < 64; s <<= 1) sum += __shfl_xor(sum, s);
    const float Z = sum + ((ninact > 0.5f) ? ninact * __expf(-M) : 0.f);
    const float inv = 1.f / (sum + 1e-13f * Z);
    u16x8 h;
#pragma unroll
    for (int k = 0; k < 8; ++k) h[k] = f2bf(p[k] * inv);
    *(u16x8*)(Wg + ((size_t)bz * LSEQ + r) * LSEQ + lane * 8) = h;
  }
}

// ---- PV GEMM: out[b][m][d] = (sum_n W[m,n]*Vt[d,n]) * maskM[m] ----
// 128x128 tile, 4 waves (64x64 quadrant each), BK=32, global_load_lds staging
__global__ __launch_bounds__(256) void k_pv(
    const unsigned short* __restrict__ Wg,   // [nb][512][512] bf16
    const unsigned short* __restrict__ Vt,   // [nb][768][512] bf16
    const int* __restrict__ maskM,           // [B][512]
    float* __restrict__ out,                 // [B][512][768]
    int b0) {
  __shared__ unsigned short Al[128 * 32];
  __shared__ unsigned short Bl[128 * 32];
  __shared__ float maskMf[128];
  const int bz = blockIdx.z;
  const int m0 = blockIdx.x * 128;
  const int d0 = blockIdx.y * 128;
  const int tid = threadIdx.x;
  const int lane = tid & 63;
  const int w = tid >> 6;
  const int wm = (w & 1) * 64, wd = (w >> 1) * 64;
  const int l15 = lane & 15, kg = lane >> 4;
  if (tid < 128) maskMf[tid] = (float)maskM[(size_t)(b0 + bz) * LSEQ + m0 + tid];
  const unsigned short* Wb = Wg + ((size_t)bz * LSEQ + m0) * LSEQ;
  const unsigned short* Vb = Vt + ((size_t)bz * DMODEL + d0) * LSEQ;
  f32x4 acc[4][4] = {};
  for (int k0 = 0; k0 < LSEQ; k0 += 32) {
    __syncthreads();  // prev iter's ds_reads done
#pragma unroll
    for (int q = 0; q < 2; ++q) {
      const int t2 = q * 256 + tid;
      const int row = t2 >> 2, cp = (t2 & 3) * 8;
      gload16(Wb + (size_t)row * LSEQ + k0 + cp, &Al[t2 * 8]);
      gload16(Vb + (size_t)row * LSEQ + k0 + cp, &Bl[t2 * 8]);
    }
    __syncthreads();  // drain global_load_lds + barrier
    bf16x8 a[4], bb[4];
#pragma unroll
    for (int f = 0; f < 4; ++f) {
      a[f]  = *(const bf16x8*)&Al[(wm + f * 16 + l15) * 32 + kg * 8];
      bb[f] = *(const bf16x8*)&Bl[(wd + f * 16 + l15) * 32 + kg * 8];
    }
#pragma unroll
    for (int fm = 0; fm < 4; ++fm)
#pragma unroll
      for (int fd = 0; fd < 4; ++fd)
        acc[fm][fd] = __builtin_amdgcn_mfma_f32_16x16x32_bf16(a[fm], bb[fd], acc[fm][fd], 0, 0, 0);
  }
  const int r4 = (lane >> 4) * 4;
#pragma unroll
  for (int fm = 0; fm < 4; ++fm)
#pragma unroll
    for (int fd = 0; fd < 4; ++fd)
#pragma unroll
      for (int reg = 0; reg < 4; ++reg) {
        const int row = wm + fm * 16 + r4 + reg;
        const int col = wd + fd * 16 + l15;
        out[((size_t)(b0 + bz) * LSEQ + m0 + row) * DMODEL + d0 + col] =
            acc[fm][fd][reg] * maskMf[row];
      }
}

extern "C" void kernel_launch(void* const* d_in, const int* in_sizes, int n_in,
                              void* d_out, int out_size, void* d_ws, size_t ws_size,
                              hipStream_t stream) {
  const float* context = (const float*)d_in[0];
  const float* response = (const float*)d_in[1];
  const int* cmask = (const int*)d_in[2];
  const int* rmask = (const int*)d_in[3];
  float* out = (float*)d_out;

  // ws per batch: S + ST fp32 + RT + CT bf16 + Wc + Wr bf16
  const size_t perBatch = (size_t)2 * LSEQ * LSEQ * 4 +
                          (size_t)2 * DMODEL * LSEQ * 2 +
                          (size_t)2 * LSEQ * LSEQ * 2;
  int nbc = (int)(ws_size / perBatch);
  if (nbc > BATCH) nbc = BATCH;
  if (nbc < 1) nbc = 1;

  char* base = (char*)d_ws;
  const size_t szS = (size_t)nbc * LSEQ * LSEQ * 4;
  const size_t szT = (size_t)nbc * DMODEL * LSEQ * 2;
  const size_t szW = (size_t)nbc * LSEQ * LSEQ * 2;
  float* S = (float*)base;
  float* ST = (float*)(base + szS);
  unsigned short* RT = (unsigned short*)(base + 2 * szS);
  unsigned short* CT = (unsigned short*)(base + 2 * szS + szT);
  unsigned short* Wc = (unsigned short*)(base + 2 * szS + 2 * szT);
  unsigned short* Wr = (unsigned short*)(base + 2 * szS + 2 * szT + szW);

  float* out_c = out;
  float* out_r = out + (size_t)BATCH * LSEQ * DMODEL;

  for (int b0 = 0; b0 < BATCH; b0 += nbc) {
    int nb = BATCH - b0;
    if (nb > nbc) nb = nbc;
    dim3 blk(256);
    k_prep_transpose<<<dim3(8, 12, nb), blk, 0, stream>>>(response, RT, b0);
    k_prep_transpose<<<dim3(8, 12, nb), blk, 0, stream>>>(context, CT, b0);
    k_gemm_s<<<dim3(8, 8, nb), blk, 0, stream>>>(context, response, S, b0);
    k_transpose_s<<<dim3(8, 8, nb), blk, 0, stream>>>(S, ST);
    k_softmax<<<dim3(8, 1, nb), blk, 0, stream>>>(S, rmask, Wc, b0);
    k_softmax<<<dim3(8, 1, nb), blk, 0, stream>>>(ST, cmask, Wr, b0);
    k_pv<<<dim3(4, 6, nb), blk, 0, stream>>>(Wc, RT, cmask, out_c, b0);
    k_pv<<<dim3(4, 6, nb), blk, 0, stream>>>(Wr, CT, rmask, out_r, b0);
  }
}